// Round 6
// baseline (311.033 us; speedup 1.0000x reference)
//
#include <hip/hip_runtime.h>
#include <math.h>

// GoBERT: GATConv(4x32) -> BN -> GCNConv(128) -> BN -> GlobalAttention -> FC
// Round 5: 128-row MFMA tiles (halve B staging); mode-1 GEMM drops zero
// column-tile; GAT output stored bf16 (halves GEMM2 A traffic); prep+bhist
// fused into one atomic-free launch (no memset); 9 dispatches total.

#define NEG_SLOPE 0.2f
#define BKT_BITS 7
#define BKT_SIZE 128
#define CHUNK_A 4096

typedef __attribute__((ext_vector_type(8))) short short8v;
typedef __attribute__((ext_vector_type(4))) float floatx4;

__device__ __forceinline__ int lower_bound_i(const int* a, int n, int key) {
    int lo = 0, hi = n;
    while (lo < hi) {
        int mid = (lo + hi) >> 1;
        if (a[mid] < key) lo = mid + 1; else hi = mid;
    }
    return lo;
}

__device__ __forceinline__ unsigned pack_bf16(float lo, float hi) {
    unsigned ua = __float_as_uint(lo);
    unsigned ub = __float_as_uint(hi);
    ua = ua + 0x7fffu + ((ua >> 16) & 1u);
    ub = ub + 0x7fffu + ((ub >> 16) & 1u);
    return (ua >> 16) | (ub & 0xffff0000u);
}

__device__ __forceinline__ unsigned short bf16_1(float v) {
    unsigned u = __float_as_uint(v);
    u = u + 0x7fffu + ((u >> 16) & 1u);
    return (unsigned short)(u >> 16);
}

// ---------------- front: weight prep (blocks 0-1) + bucket hist (rest) -----
// Wt1[144][128]: rows 0-127 = W_gat^T; 128-131 = W@att_src; 132-135 =
// W@att_dst; 136-143 = 0.  Wt2[128][128] = W_gcn^T.
// bhists[slice][512]: per-block bucket histograms (no global atomics).
__global__ __launch_bounds__(256) void k_front(
    const float* __restrict__ W1, const float* __restrict__ atts,
    const float* __restrict__ attd, const float* __restrict__ W2,
    unsigned short* __restrict__ Wt1, unsigned short* __restrict__ Wt2,
    const int* __restrict__ dst, int* __restrict__ bhists, int E)
{
    const int b = blockIdx.x;
    if (b < 2) {
        const float* W = b ? W2 : W1;
        unsigned short* Wt = b ? Wt2 : Wt1;
        const int lim = b ? (128 * 128) : (144 * 128);
        for (int idx = threadIdx.x; idx < lim; idx += 256) {
            int j = idx >> 7, i = idx & 127;
            float v;
            if (j < 128) v = W[i * 128 + j];
            else if (j < 132) {
                int h = j - 128; float s = 0.f;
                for (int c = 0; c < 32; c++) s += W1[i * 128 + h * 32 + c] * atts[h * 32 + c];
                v = s;
            } else if (j < 136) {
                int h = j - 132; float s = 0.f;
                for (int c = 0; c < 32; c++) s += W1[i * 128 + h * 32 + c] * attd[h * 32 + c];
                v = s;
            } else v = 0.f;
            Wt[idx] = bf16_1(v);
        }
    } else {
        __shared__ int h[512];
        const int tid = threadIdx.x;
        for (int i = tid; i < 512; i += 256) h[i] = 0;
        __syncthreads();
        int base = (b - 2) * 2048;
#pragma unroll
        for (int k = 0; k < 8; k++) {
            int e = base + k * 256 + tid;
            if (e < E) atomicAdd(&h[dst[e] >> BKT_BITS], 1);
        }
        __syncthreads();
        int* slice = bhists + (size_t)(b - 2) * 512;
        for (int i = tid; i < 512; i += 256) slice[i] = h[i];
    }
}

// ---------------- MFMA GEMM: 128 rows/block, Cb[N,64 pairs] ----------------
// Pair t of row n = channels (t, t+64). MODE 0: fp32 A in; aS/aD from ct=8.
// MODE 1: bf16 A in; f = bn1*elu(a+b_gat)+bn1b, s = dinv[row]; NCT=8.
template<int MODE>
__global__ __launch_bounds__(256) void k_gemm_mfma(
    const void* __restrict__ Ain, const unsigned short* __restrict__ Wt,
    unsigned* __restrict__ Cb, int N,
    const float* __restrict__ pb, const float* __restrict__ pw,
    const float* __restrict__ pb2, const float* __restrict__ dinv,
    float* __restrict__ aS, float* __restrict__ aD)
{
    constexpr int NCT = (MODE == 0) ? 9 : 8;
    __shared__ unsigned short sA[128 * 136];
    __shared__ unsigned short sB[NCT * 16 * 136];
    const int tid = threadIdx.x;
    const int n0 = blockIdx.x * 128;

    // stage B (coalesced uint4, LDS row stride 136)
    {
        const uint4* Wg = (const uint4*)Wt;
        const int nq = NCT * 16 * 16;
        for (int q = tid; q < nq; q += 256) {
            uint4 v = Wg[q];
            int j = q >> 4, seg = q & 15;
            *(uint4*)(sB + j * 136 + seg * 8) = v;
        }
    }
    // stage A
    if (MODE == 0) {
        const float* A = (const float*)Ain;
        const int w4 = tid & 31;          // float4 within row
        const int r0 = tid >> 5;          // 0..7
#pragma unroll
        for (int i = 0; i < 16; i++) {
            int r = r0 + 8 * i;
            int gn = n0 + r;
            unsigned p0 = 0, p1 = 0;
            if (gn < N) {
                float4 v = *(const float4*)(A + (size_t)gn * 128 + w4 * 4);
                p0 = pack_bf16(v.x, v.y);
                p1 = pack_bf16(v.z, v.w);
            }
            *(uint2*)(sA + r * 136 + w4 * 4) = make_uint2(p0, p1);
        }
    } else {
        const unsigned short* A = (const unsigned short*)Ain;
        const int w8 = tid & 15;          // 8-channel group within row
        const int r0 = tid >> 4;          // 0..15
        const int k0 = w8 * 8;
        float pbv[8], pwv[8], p2v[8];
        *(float4*)(pbv)     = *(const float4*)(pb + k0);
        *(float4*)(pbv + 4) = *(const float4*)(pb + k0 + 4);
        *(float4*)(pwv)     = *(const float4*)(pw + k0);
        *(float4*)(pwv + 4) = *(const float4*)(pw + k0 + 4);
        *(float4*)(p2v)     = *(const float4*)(pb2 + k0);
        *(float4*)(p2v + 4) = *(const float4*)(pb2 + k0 + 4);
#pragma unroll
        for (int i = 0; i < 8; i++) {
            int r = r0 + 16 * i;
            int gn = n0 + r;
            uint4 outv = make_uint4(0, 0, 0, 0);
            if (gn < N) {
                uint4 v = *(const uint4*)(A + (size_t)gn * 128 + k0);
                unsigned uu[4] = {v.x, v.y, v.z, v.w};
                unsigned ro[4];
#pragma unroll
                for (int q2 = 0; q2 < 4; q2++) {
                    float lo = __uint_as_float(uu[q2] << 16);
                    float hi = __uint_as_float(uu[q2] & 0xffff0000u);
                    float t;
                    t = lo + pbv[2 * q2];     t = (t > 0.f) ? t : expm1f(t); lo = t * pwv[2 * q2]     + p2v[2 * q2];
                    t = hi + pbv[2 * q2 + 1]; t = (t > 0.f) ? t : expm1f(t); hi = t * pwv[2 * q2 + 1] + p2v[2 * q2 + 1];
                    ro[q2] = pack_bf16(lo, hi);
                }
                outv = make_uint4(ro[0], ro[1], ro[2], ro[3]);
            }
            *(uint4*)(sA + r * 136 + k0) = outv;
        }
    }
    __syncthreads();

    const int wid = tid >> 6, lane = tid & 63;
    const int quad = lane >> 4, l16 = lane & 15;

    floatx4 acc[2][NCT];
#pragma unroll
    for (int rt = 0; rt < 2; rt++)
#pragma unroll
        for (int ct = 0; ct < NCT; ct++) acc[rt][ct] = (floatx4){0.f, 0.f, 0.f, 0.f};

    const unsigned short* pa0 = sA + (wid * 32 + l16) * 136 + quad * 8;
    const unsigned short* pbt = sB + l16 * 136 + quad * 8;
#pragma unroll
    for (int ks = 0; ks < 4; ks++) {
        short8v a0 = *(const short8v*)(pa0 + ks * 32);
        short8v a1 = *(const short8v*)(pa0 + 16 * 136 + ks * 32);
#pragma unroll
        for (int ct = 0; ct < NCT; ct++) {
            short8v bv = *(const short8v*)(pbt + ct * (16 * 136) + ks * 32);
            acc[0][ct] = __builtin_amdgcn_mfma_f32_16x16x32_bf16(a0, bv, acc[0][ct], 0, 0, 0);
            acc[1][ct] = __builtin_amdgcn_mfma_f32_16x16x32_bf16(a1, bv, acc[1][ct], 0, 0, 0);
        }
    }

    // epilogue: lane = rows quad*4+r, col ct*16+l16
#pragma unroll
    for (int rt = 0; rt < 2; rt++) {
#pragma unroll
        for (int r = 0; r < 4; r++) {
            int n = n0 + wid * 32 + rt * 16 + quad * 4 + r;
            if (n >= N) continue;
            float s = MODE ? dinv[n] : 1.f;
#pragma unroll
            for (int ct = 0; ct < 4; ct++) {
                Cb[(size_t)n * 64 + ct * 16 + l16] =
                    pack_bf16(acc[rt][ct][r] * s, acc[rt][ct + 4][r] * s);
            }
            if (MODE == 0) {
                float e = acc[rt][8][r];
                if (l16 < 4) aS[(size_t)n * 4 + l16] = e;
                else if (l16 < 8) aD[(size_t)n * 4 + (l16 - 4)] = e;
            }
        }
    }
}

// ---------------- CSR build ----------------
__global__ __launch_bounds__(512) void k_bscan(const int* __restrict__ bhists,
                                               int nslices,
                                               int* __restrict__ bb,
                                               int* __restrict__ bcur, int NB)
{
    __shared__ int sc[512];
    const int tid = threadIdx.x;
    int own = 0;
    for (int s = 0; s < nslices; s++) own += bhists[(size_t)s * 512 + tid];
    sc[tid] = own;
    __syncthreads();
    for (int st = 1; st < 512; st <<= 1) {
        int v = 0;
        if (tid >= st) v = sc[tid - st];
        __syncthreads();
        if (tid >= st) sc[tid] += v;
        __syncthreads();
    }
    int excl = sc[tid] - own;
    if (tid < NB) { bb[tid] = excl; bcur[tid] = excl; }
    if (tid == 511) { bb[NB] = sc[511]; bcur[NB] = sc[511]; }
}

__global__ __launch_bounds__(256) void k_binA(const int* __restrict__ ei,
                                              int* __restrict__ bcur,
                                              int2* __restrict__ pairs,
                                              int E, int NB)
{
    __shared__ int h[512];
    __shared__ int base[512];
    const int tid = threadIdx.x;
    for (int i = tid; i < NB + 1; i += 256) h[i] = 0;
    __syncthreads();
    const int c0 = blockIdx.x * CHUNK_A;
    int s[16], d[16], b[16];
#pragma unroll
    for (int k = 0; k < 16; k++) {
        int e = c0 + k * 256 + tid;
        bool v = e < E;
        s[k] = v ? ei[e] : 0;
        d[k] = v ? ei[E + e] : 0;
        b[k] = v ? (d[k] >> BKT_BITS) : NB;
        atomicAdd(&h[b[k]], 1);
    }
    __syncthreads();
    for (int i = tid; i < NB + 1; i += 256) {
        int c = h[i];
        base[i] = c ? atomicAdd(&bcur[i], c) : 0;
        h[i] = 0;
    }
    __syncthreads();
#pragma unroll
    for (int k = 0; k < 16; k++) {
        int r = atomicAdd(&h[b[k]], 1);
        pairs[base[b[k]] + r] = make_int2(s[k], d[k]);
    }
}

__global__ __launch_bounds__(256) void k_binB(const int2* __restrict__ pairs,
                                              const int* __restrict__ bb,
                                              int* __restrict__ csr,
                                              int* __restrict__ offs,
                                              float* __restrict__ dinv,
                                              int N, int NB, int E)
{
    __shared__ int hist[BKT_SIZE], start[BKT_SIZE], cur[BKT_SIZE];
    __shared__ int sc[BKT_SIZE];
    const int tid = threadIdx.x;
    const int b = blockIdx.x;
    const int d0 = b << BKT_BITS;
    const int pbg = bb[b], peg = bb[b + 1];

    if (tid < BKT_SIZE) { hist[tid] = 0; cur[tid] = 0; }
    __syncthreads();
    for (int i = pbg + tid; i < peg; i += 256)
        atomicAdd(&hist[pairs[i].y - d0], 1);
    __syncthreads();
    int own = (tid < BKT_SIZE) ? hist[tid] : 0;
    if (tid < BKT_SIZE) sc[tid] = own;
    __syncthreads();
    for (int st = 1; st < BKT_SIZE; st <<= 1) {
        int v = 0;
        bool act = (tid < BKT_SIZE) && (tid >= st);
        if (act) v = sc[tid - st];
        __syncthreads();
        if (act) sc[tid] += v;
        __syncthreads();
    }
    if (tid < BKT_SIZE) {
        int abs0 = pbg + (sc[tid] - own);
        start[tid] = abs0;
        int d = d0 + tid;
        if (d < N) {
            offs[d] = abs0;
            dinv[d] = rsqrtf((float)(own + 1));
        }
    }
    if (tid == 0 && b == NB - 1) offs[N] = E;
    __syncthreads();
    for (int i = pbg + tid; i < peg; i += 256) {
        int2 p = pairs[i];
        int ld = p.y - d0;
        int r = atomicAdd(&cur[ld], 1);
        csr[start[ld] + r] = p.x;
    }
}

// ---------------- GAT aggregation: 4 nodes / 256-thread block --------------
// hb pair t = channels (t, t+64); lane l owns (l, l+64); hA = l>>5.
// Output raw1b: bf16, channel-ordered.
__global__ __launch_bounds__(256) void k_gat_aggr(
    const unsigned* __restrict__ hb, const float* __restrict__ aSg,
    const float* __restrict__ aDg, const int* __restrict__ offs,
    const int* __restrict__ csr, unsigned short* __restrict__ raw1b, int N)
{
    __shared__ __align__(16) float s_u[4][64][4];   // (u0,u2,u1,u3)
    __shared__ int s_s[4][64];

    const int wid = threadIdx.x >> 6;
    const int lane = threadIdx.x & 63;
    const int n = blockIdx.x * 4 + wid;
    if (n >= N) return;

    const int beg = offs[n];
    const int cnt = offs[n + 1] - beg + 1;          // + self loop
    const float4 ad = *(const float4*)(aDg + (size_t)n * 4);
    const int hA = lane >> 5;
    const float* pu = &s_u[wid][0][2 * hA];
    const int* ps = &s_s[wid][0];

    float t0 = 0.f, t1 = 0.f, t2 = 0.f, t3 = 0.f;
    float accLo = 0.f, accHi = 0.f;

    for (int base = 0; base < cnt; base += 64) {
        int idx = base + lane;
        bool valid = idx < cnt;
        int src = n;
        if (valid && idx > 0) src = csr[beg + idx - 1];
        float u0 = 0.f, u1 = 0.f, u2 = 0.f, u3 = 0.f;
        if (valid) {
            float4 as = *(const float4*)(aSg + (size_t)src * 4);
            float l0 = as.x + ad.x; l0 = (l0 > 0.f) ? l0 : NEG_SLOPE * l0;
            float l1 = as.y + ad.y; l1 = (l1 > 0.f) ? l1 : NEG_SLOPE * l1;
            float l2 = as.z + ad.z; l2 = (l2 > 0.f) ? l2 : NEG_SLOPE * l2;
            float l3 = as.w + ad.w; l3 = (l3 > 0.f) ? l3 : NEG_SLOPE * l3;
            u0 = __expf(l0); u1 = __expf(l1); u2 = __expf(l2); u3 = __expf(l3);
        }
        t0 += u0; t1 += u1; t2 += u2; t3 += u3;
        s_s[wid][lane] = src;
        *(float4*)&s_u[wid][lane][0] = make_float4(u0, u2, u1, u3);

        int cc = min(64, cnt - base);
        int j = 0;
        for (; j + 8 <= cc; j += 8) {
            int sj[8]; float2 uj[8]; unsigned vv[8];
#pragma unroll
            for (int k = 0; k < 8; k++) sj[k] = ps[j + k];
#pragma unroll
            for (int k = 0; k < 8; k++) uj[k] = *(const float2*)&pu[(j + k) * 4];
#pragma unroll
            for (int k = 0; k < 8; k++) vv[k] = hb[sj[k] * 64 + lane];
#pragma unroll
            for (int k = 0; k < 8; k++) {
                float lo = __uint_as_float(vv[k] << 16);
                float hi = __uint_as_float(vv[k] & 0xffff0000u);
                accLo += uj[k].x * lo;
                accHi += uj[k].y * hi;
            }
        }
        for (; j < cc; j++) {
            int sj = ps[j];
            float2 uv = *(const float2*)&pu[j * 4];
            unsigned v = hb[sj * 64 + lane];
            accLo += uv.x * __uint_as_float(v << 16);
            accHi += uv.y * __uint_as_float(v & 0xffff0000u);
        }
    }
#pragma unroll
    for (int msk = 1; msk < 64; msk <<= 1) {
        t0 += __shfl_xor(t0, msk);
        t1 += __shfl_xor(t1, msk);
        t2 += __shfl_xor(t2, msk);
        t3 += __shfl_xor(t3, msk);
    }
    float sLo = (hA ? t1 : t0) + 1e-16f;
    float sHi = (hA ? t3 : t2) + 1e-16f;
    raw1b[(size_t)n * 128 + lane]      = bf16_1(accLo / sLo);
    raw1b[(size_t)n * 128 + 64 + lane] = bf16_1(accHi / sHi);
}

// ---------------- GCN aggregation + fused BN2/ELU/gate/fc ------------------
__global__ __launch_bounds__(256) void k_gcn_aggr(
    const unsigned* __restrict__ h2b, const int* __restrict__ offs,
    const int* __restrict__ csr, const float* __restrict__ dinv,
    const float* __restrict__ bgcn,
    const float* __restrict__ bn2w, const float* __restrict__ bn2b,
    const float* __restrict__ wgate, const float* __restrict__ bgate,
    const float* __restrict__ wfc,
    float* __restrict__ gate, float* __restrict__ fcdot, int N)
{
    __shared__ int s_s[4][64];

    const int wid = threadIdx.x >> 6;
    const int lane = threadIdx.x & 63;
    const int n = blockIdx.x * 4 + wid;
    if (n >= N) return;

    const int beg = offs[n];
    const int cnt = offs[n + 1] - beg + 1;
    const float dn = dinv[n];
    const int* ps = &s_s[wid][0];

    float accLo = 0.f, accHi = 0.f;
    for (int base = 0; base < cnt; base += 64) {
        int idx = base + lane;
        int src = n;
        if (idx > 0 && idx < cnt) src = csr[beg + idx - 1];
        s_s[wid][lane] = src;

        int cc = min(64, cnt - base);
        int j = 0;
        for (; j + 8 <= cc; j += 8) {
            int sj[8]; unsigned vv[8];
#pragma unroll
            for (int k = 0; k < 8; k++) sj[k] = ps[j + k];
#pragma unroll
            for (int k = 0; k < 8; k++) vv[k] = h2b[sj[k] * 64 + lane];
#pragma unroll
            for (int k = 0; k < 8; k++) {
                accLo += __uint_as_float(vv[k] << 16);
                accHi += __uint_as_float(vv[k] & 0xffff0000u);
            }
        }
        for (; j < cc; j++) {
            unsigned v = h2b[ps[j] * 64 + lane];
            accLo += __uint_as_float(v << 16);
            accHi += __uint_as_float(v & 0xffff0000u);
        }
    }
    float v0 = dn * accLo + bgcn[lane];
    v0 = (v0 > 0.f) ? v0 : expm1f(v0);
    v0 = v0 * bn2w[lane] + bn2b[lane];
    float v1 = dn * accHi + bgcn[lane + 64];
    v1 = (v1 > 0.f) ? v1 : expm1f(v1);
    v1 = v1 * bn2w[lane + 64] + bn2b[lane + 64];

    float g = v0 * wgate[lane] + v1 * wgate[lane + 64];
    float f = v0 * wfc[lane]   + v1 * wfc[lane + 64];
#pragma unroll
    for (int msk = 1; msk < 64; msk <<= 1) {
        g += __shfl_xor(g, msk);
        f += __shfl_xor(f, msk);
    }
    if (lane == 0) { gate[n] = g + bgate[0]; fcdot[n] = f; }
}

// ---------------- pooling softmax over scalars: one block / graph ----------
__global__ __launch_bounds__(256) void k_pool(
    const float* __restrict__ gate, const float* __restrict__ fcdot,
    const int* __restrict__ batch, const float* __restrict__ bfc,
    float* __restrict__ out, int N)
{
    __shared__ float red[256];
    __shared__ int range[2];
    const int g = blockIdx.x;
    const int tid = threadIdx.x;
    if (tid < 2) range[tid] = lower_bound_i(batch, N, g + tid);
    __syncthreads();
    const int lo = range[0], hi = range[1];
    float se = 0.f, sf = 0.f;
    for (int i = lo + tid; i < hi; i += 256) {
        float e = __expf(gate[i]);
        se += e;
        sf += e * fcdot[i];
    }
    red[tid] = se; __syncthreads();
    for (int s = 128; s > 0; s >>= 1) {
        if (tid < s) red[tid] += red[tid + s];
        __syncthreads();
    }
    se = red[0]; __syncthreads();
    red[tid] = sf; __syncthreads();
    for (int s = 128; s > 0; s >>= 1) {
        if (tid < s) red[tid] += red[tid + s];
        __syncthreads();
    }
    sf = red[0];
    if (tid == 0) out[g] = sf / (se + 1e-16f) + bfc[0];
}

// ---------------------------------------------------------------------------
extern "C" void kernel_launch(void* const* d_in, const int* in_sizes, int n_in,
                              void* d_out, int out_size, void* d_ws, size_t ws_size,
                              hipStream_t stream) {
    const float* x     = (const float*)d_in[0];
    const int*   ei    = (const int*)d_in[1];
    const int*   batch = (const int*)d_in[2];
    const float* Wgat  = (const float*)d_in[3];
    const float* atts  = (const float*)d_in[4];
    const float* attd  = (const float*)d_in[5];
    const float* bgat  = (const float*)d_in[6];
    const float* bn1w  = (const float*)d_in[7];
    const float* bn1b  = (const float*)d_in[8];
    const float* Wgcn  = (const float*)d_in[9];
    const float* bgcn  = (const float*)d_in[10];
    const float* bn2w  = (const float*)d_in[11];
    const float* bn2b  = (const float*)d_in[12];
    const float* wgate = (const float*)d_in[13];
    const float* bgate = (const float*)d_in[14];
    const float* wfc   = (const float*)d_in[15];
    const float* bfc   = (const float*)d_in[16];
    float* out = (float*)d_out;

    const int N = in_sizes[0] / 128;
    const int E = in_sizes[1] / 2;
    const int NB = (N + BKT_SIZE - 1) / BKT_SIZE;
    const int NHB = (E + 2047) / 2048;             // bhist slices

    unsigned* hb  = (unsigned*)d_ws;               // bf16 h table   [N*64]
    unsigned* h2b = hb + (size_t)N * 64;           // bf16 h2s table [N*64]
    unsigned short* raw1b = (unsigned short*)(h2b + (size_t)N * 64); // [N*128]
    int2* pairs  = (int2*)raw1b;                   // aliased: pre-GAT only
    float* aS    = (float*)(raw1b + (size_t)N * 128); // [N*4]
    float* aD    = aS + (size_t)N * 4;             // [N*4]
    float* gate  = aD + (size_t)N * 4;             // [N]
    float* fcdot = gate + N;                       // [N]
    float* dinv  = fcdot + N;                      // [N]
    int* offs   = (int*)(dinv + N);                // [N+1]
    int* csr    = offs + (N + 1);                  // [E]
    int* bb     = csr + E;                         // [NB+1]
    int* bcur   = bb + (NB + 1);                   // [NB+1]
    int* bhists = bcur + (NB + 1);                 // [NHB*512]
    unsigned short* Wt1 = (unsigned short*)(bhists + (size_t)NHB * 512); // [144*128]
    unsigned short* Wt2 = Wt1 + 144 * 128;                               // [128*128]

    const int gemm_blocks = (N + 127) / 128;
    const int aggr_blocks = (N + 3) / 4;

    k_front<<<NHB + 2, 256, 0, stream>>>(Wgat, atts, attd, Wgcn, Wt1, Wt2,
                                         ei + E, bhists, E);
    k_gemm_mfma<0><<<gemm_blocks, 256, 0, stream>>>(x, Wt1, hb, N,
                                                    nullptr, nullptr, nullptr,
                                                    nullptr, aS, aD);
    k_bscan<<<1, 512, 0, stream>>>(bhists, NHB, bb, bcur, NB);
    k_binA<<<(E + CHUNK_A - 1) / CHUNK_A, 256, 0, stream>>>(ei, bcur, pairs, E, NB);
    k_binB<<<NB, 256, 0, stream>>>(pairs, bb, csr, offs, dinv, N, NB, E);
    k_gat_aggr<<<aggr_blocks, 256, 0, stream>>>(hb, aS, aD, offs, csr, raw1b, N);
    k_gemm_mfma<1><<<gemm_blocks, 256, 0, stream>>>(raw1b, Wt2, h2b, N,
                                                    bgat, bn1w, bn1b, dinv,
                                                    nullptr, nullptr);
    k_gcn_aggr<<<aggr_blocks, 256, 0, stream>>>(h2b, offs, csr, dinv, bgcn,
                                                bn2w, bn2b, wgate, bgate, wfc,
                                                gate, fcdot, N);
    k_pool<<<64, 256, 0, stream>>>(gate, fcdot, batch, bfc, out, N);
}

// Round 7
// 264.377 us; speedup vs baseline: 1.1765x; 1.1765x over previous
//
#include <hip/hip_runtime.h>
#include <math.h>

// GoBERT: GATConv(4x32) -> BN -> GCNConv(128) -> BN -> GlobalAttention -> FC
// Round 6 fix: revert histogram to global-atomic bcount (the "atomic-free"
// slice reduction made k_bscan a 58us serial latency chain). Keep 128-row
// MFMA tiles, bf16 raw1, NCT=8, fused prep+hist launch.

#define NEG_SLOPE 0.2f
#define BKT_BITS 7
#define BKT_SIZE 128
#define CHUNK_A 4096

typedef __attribute__((ext_vector_type(8))) short short8v;
typedef __attribute__((ext_vector_type(4))) float floatx4;

__device__ __forceinline__ int lower_bound_i(const int* a, int n, int key) {
    int lo = 0, hi = n;
    while (lo < hi) {
        int mid = (lo + hi) >> 1;
        if (a[mid] < key) lo = mid + 1; else hi = mid;
    }
    return lo;
}

__device__ __forceinline__ unsigned pack_bf16(float lo, float hi) {
    unsigned ua = __float_as_uint(lo);
    unsigned ub = __float_as_uint(hi);
    ua = ua + 0x7fffu + ((ua >> 16) & 1u);
    ub = ub + 0x7fffu + ((ub >> 16) & 1u);
    return (ua >> 16) | (ub & 0xffff0000u);
}

__device__ __forceinline__ unsigned short bf16_1(float v) {
    unsigned u = __float_as_uint(v);
    u = u + 0x7fffu + ((u >> 16) & 1u);
    return (unsigned short)(u >> 16);
}

// ---------------- front: weight prep (blocks 0-1) + bucket hist (rest) -----
// Wt1[144][128]: rows 0-127 = W_gat^T; 128-131 = W@att_src; 132-135 =
// W@att_dst; 136-143 = 0.  Wt2[128][128] = W_gcn^T.
// Histogram: per-block LDS, then global atomicAdd into bcount (few hundred
// atomics/block — measured fine in r4/r5; do NOT serialize into one WG).
__global__ __launch_bounds__(256) void k_front(
    const float* __restrict__ W1, const float* __restrict__ atts,
    const float* __restrict__ attd, const float* __restrict__ W2,
    unsigned short* __restrict__ Wt1, unsigned short* __restrict__ Wt2,
    const int* __restrict__ dst, int* __restrict__ bcount, int E, int NB)
{
    const int b = blockIdx.x;
    if (b < 2) {
        const float* W = b ? W2 : W1;
        unsigned short* Wt = b ? Wt2 : Wt1;
        const int lim = b ? (128 * 128) : (144 * 128);
        for (int idx = threadIdx.x; idx < lim; idx += 256) {
            int j = idx >> 7, i = idx & 127;
            float v;
            if (j < 128) v = W[i * 128 + j];
            else if (j < 132) {
                int h = j - 128; float s = 0.f;
                for (int c = 0; c < 32; c++) s += W1[i * 128 + h * 32 + c] * atts[h * 32 + c];
                v = s;
            } else if (j < 136) {
                int h = j - 132; float s = 0.f;
                for (int c = 0; c < 32; c++) s += W1[i * 128 + h * 32 + c] * attd[h * 32 + c];
                v = s;
            } else v = 0.f;
            Wt[idx] = bf16_1(v);
        }
    } else {
        __shared__ int h[512];
        const int tid = threadIdx.x;
        for (int i = tid; i < 512; i += 256) h[i] = 0;
        __syncthreads();
        int base = (b - 2) * 2048;
#pragma unroll
        for (int k = 0; k < 8; k++) {
            int e = base + k * 256 + tid;
            if (e < E) atomicAdd(&h[dst[e] >> BKT_BITS], 1);
        }
        __syncthreads();
        for (int i = tid; i < NB; i += 256) {
            int c = h[i];
            if (c) atomicAdd(&bcount[i], c);
        }
    }
}

// ---------------- MFMA GEMM: 128 rows/block, Cb[N,64 pairs] ----------------
// Pair t of row n = channels (t, t+64). MODE 0: fp32 A in; aS/aD from ct=8.
// MODE 1: bf16 A in; f = bn1*elu(a+b_gat)+bn1b, s = dinv[row]; NCT=8.
template<int MODE>
__global__ __launch_bounds__(256) void k_gemm_mfma(
    const void* __restrict__ Ain, const unsigned short* __restrict__ Wt,
    unsigned* __restrict__ Cb, int N,
    const float* __restrict__ pb, const float* __restrict__ pw,
    const float* __restrict__ pb2, const float* __restrict__ dinv,
    float* __restrict__ aS, float* __restrict__ aD)
{
    constexpr int NCT = (MODE == 0) ? 9 : 8;
    __shared__ unsigned short sA[128 * 136];
    __shared__ unsigned short sB[NCT * 16 * 136];
    const int tid = threadIdx.x;
    const int n0 = blockIdx.x * 128;

    // stage B (coalesced uint4, LDS row stride 136)
    {
        const uint4* Wg = (const uint4*)Wt;
        const int nq = NCT * 16 * 16;
        for (int q = tid; q < nq; q += 256) {
            uint4 v = Wg[q];
            int j = q >> 4, seg = q & 15;
            *(uint4*)(sB + j * 136 + seg * 8) = v;
        }
    }
    // stage A
    if (MODE == 0) {
        const float* A = (const float*)Ain;
        const int w4 = tid & 31;          // float4 within row
        const int r0 = tid >> 5;          // 0..7
#pragma unroll
        for (int i = 0; i < 16; i++) {
            int r = r0 + 8 * i;
            int gn = n0 + r;
            unsigned p0 = 0, p1 = 0;
            if (gn < N) {
                float4 v = *(const float4*)(A + (size_t)gn * 128 + w4 * 4);
                p0 = pack_bf16(v.x, v.y);
                p1 = pack_bf16(v.z, v.w);
            }
            *(uint2*)(sA + r * 136 + w4 * 4) = make_uint2(p0, p1);
        }
    } else {
        const unsigned short* A = (const unsigned short*)Ain;
        const int w8 = tid & 15;          // 8-channel group within row
        const int r0 = tid >> 4;          // 0..15
        const int k0 = w8 * 8;
        float pbv[8], pwv[8], p2v[8];
        *(float4*)(pbv)     = *(const float4*)(pb + k0);
        *(float4*)(pbv + 4) = *(const float4*)(pb + k0 + 4);
        *(float4*)(pwv)     = *(const float4*)(pw + k0);
        *(float4*)(pwv + 4) = *(const float4*)(pw + k0 + 4);
        *(float4*)(p2v)     = *(const float4*)(pb2 + k0);
        *(float4*)(p2v + 4) = *(const float4*)(pb2 + k0 + 4);
#pragma unroll
        for (int i = 0; i < 8; i++) {
            int r = r0 + 16 * i;
            int gn = n0 + r;
            uint4 outv = make_uint4(0, 0, 0, 0);
            if (gn < N) {
                uint4 v = *(const uint4*)(A + (size_t)gn * 128 + k0);
                unsigned uu[4] = {v.x, v.y, v.z, v.w};
                unsigned ro[4];
#pragma unroll
                for (int q2 = 0; q2 < 4; q2++) {
                    float lo = __uint_as_float(uu[q2] << 16);
                    float hi = __uint_as_float(uu[q2] & 0xffff0000u);
                    float t;
                    t = lo + pbv[2 * q2];     t = (t > 0.f) ? t : expm1f(t); lo = t * pwv[2 * q2]     + p2v[2 * q2];
                    t = hi + pbv[2 * q2 + 1]; t = (t > 0.f) ? t : expm1f(t); hi = t * pwv[2 * q2 + 1] + p2v[2 * q2 + 1];
                    ro[q2] = pack_bf16(lo, hi);
                }
                outv = make_uint4(ro[0], ro[1], ro[2], ro[3]);
            }
            *(uint4*)(sA + r * 136 + k0) = outv;
        }
    }
    __syncthreads();

    const int wid = tid >> 6, lane = tid & 63;
    const int quad = lane >> 4, l16 = lane & 15;

    floatx4 acc[2][NCT];
#pragma unroll
    for (int rt = 0; rt < 2; rt++)
#pragma unroll
        for (int ct = 0; ct < NCT; ct++) acc[rt][ct] = (floatx4){0.f, 0.f, 0.f, 0.f};

    const unsigned short* pa0 = sA + (wid * 32 + l16) * 136 + quad * 8;
    const unsigned short* pbt = sB + l16 * 136 + quad * 8;
#pragma unroll
    for (int ks = 0; ks < 4; ks++) {
        short8v a0 = *(const short8v*)(pa0 + ks * 32);
        short8v a1 = *(const short8v*)(pa0 + 16 * 136 + ks * 32);
#pragma unroll
        for (int ct = 0; ct < NCT; ct++) {
            short8v bv = *(const short8v*)(pbt + ct * (16 * 136) + ks * 32);
            acc[0][ct] = __builtin_amdgcn_mfma_f32_16x16x32_bf16(a0, bv, acc[0][ct], 0, 0, 0);
            acc[1][ct] = __builtin_amdgcn_mfma_f32_16x16x32_bf16(a1, bv, acc[1][ct], 0, 0, 0);
        }
    }

    // epilogue: lane = rows quad*4+r, col ct*16+l16
#pragma unroll
    for (int rt = 0; rt < 2; rt++) {
#pragma unroll
        for (int r = 0; r < 4; r++) {
            int n = n0 + wid * 32 + rt * 16 + quad * 4 + r;
            if (n >= N) continue;
            float s = MODE ? dinv[n] : 1.f;
#pragma unroll
            for (int ct = 0; ct < 4; ct++) {
                Cb[(size_t)n * 64 + ct * 16 + l16] =
                    pack_bf16(acc[rt][ct][r] * s, acc[rt][ct + 4][r] * s);
            }
            if (MODE == 0) {
                float e = acc[rt][8][r];
                if (l16 < 4) aS[(size_t)n * 4 + l16] = e;
                else if (l16 < 8) aD[(size_t)n * 4 + (l16 - 4)] = e;
            }
        }
    }
}

// ---------------- CSR build ----------------
__global__ __launch_bounds__(512) void k_bscan(const int* __restrict__ bcount,
                                               int* __restrict__ bb,
                                               int* __restrict__ bcur, int NB)
{
    __shared__ int sc[512];
    const int tid = threadIdx.x;
    int own = (tid < NB) ? bcount[tid] : 0;
    sc[tid] = own;
    __syncthreads();
    for (int st = 1; st < 512; st <<= 1) {
        int v = 0;
        if (tid >= st) v = sc[tid - st];
        __syncthreads();
        if (tid >= st) sc[tid] += v;
        __syncthreads();
    }
    int excl = sc[tid] - own;
    if (tid < NB) { bb[tid] = excl; bcur[tid] = excl; }
    if (tid == 511) { bb[NB] = sc[511]; bcur[NB] = sc[511]; }
}

__global__ __launch_bounds__(256) void k_binA(const int* __restrict__ ei,
                                              int* __restrict__ bcur,
                                              int2* __restrict__ pairs,
                                              int E, int NB)
{
    __shared__ int h[512];
    __shared__ int base[512];
    const int tid = threadIdx.x;
    for (int i = tid; i < NB + 1; i += 256) h[i] = 0;
    __syncthreads();
    const int c0 = blockIdx.x * CHUNK_A;
    int s[16], d[16], b[16];
#pragma unroll
    for (int k = 0; k < 16; k++) {
        int e = c0 + k * 256 + tid;
        bool v = e < E;
        s[k] = v ? ei[e] : 0;
        d[k] = v ? ei[E + e] : 0;
        b[k] = v ? (d[k] >> BKT_BITS) : NB;
        atomicAdd(&h[b[k]], 1);
    }
    __syncthreads();
    for (int i = tid; i < NB + 1; i += 256) {
        int c = h[i];
        base[i] = c ? atomicAdd(&bcur[i], c) : 0;
        h[i] = 0;
    }
    __syncthreads();
#pragma unroll
    for (int k = 0; k < 16; k++) {
        int r = atomicAdd(&h[b[k]], 1);
        pairs[base[b[k]] + r] = make_int2(s[k], d[k]);
    }
}

__global__ __launch_bounds__(256) void k_binB(const int2* __restrict__ pairs,
                                              const int* __restrict__ bb,
                                              int* __restrict__ csr,
                                              int* __restrict__ offs,
                                              float* __restrict__ dinv,
                                              int N, int NB, int E)
{
    __shared__ int hist[BKT_SIZE], start[BKT_SIZE], cur[BKT_SIZE];
    __shared__ int sc[BKT_SIZE];
    const int tid = threadIdx.x;
    const int b = blockIdx.x;
    const int d0 = b << BKT_BITS;
    const int pbg = bb[b], peg = bb[b + 1];

    if (tid < BKT_SIZE) { hist[tid] = 0; cur[tid] = 0; }
    __syncthreads();
    for (int i = pbg + tid; i < peg; i += 256)
        atomicAdd(&hist[pairs[i].y - d0], 1);
    __syncthreads();
    int own = (tid < BKT_SIZE) ? hist[tid] : 0;
    if (tid < BKT_SIZE) sc[tid] = own;
    __syncthreads();
    for (int st = 1; st < BKT_SIZE; st <<= 1) {
        int v = 0;
        bool act = (tid < BKT_SIZE) && (tid >= st);
        if (act) v = sc[tid - st];
        __syncthreads();
        if (act) sc[tid] += v;
        __syncthreads();
    }
    if (tid < BKT_SIZE) {
        int abs0 = pbg + (sc[tid] - own);
        start[tid] = abs0;
        int d = d0 + tid;
        if (d < N) {
            offs[d] = abs0;
            dinv[d] = rsqrtf((float)(own + 1));
        }
    }
    if (tid == 0 && b == NB - 1) offs[N] = E;
    __syncthreads();
    for (int i = pbg + tid; i < peg; i += 256) {
        int2 p = pairs[i];
        int ld = p.y - d0;
        int r = atomicAdd(&cur[ld], 1);
        csr[start[ld] + r] = p.x;
    }
}

// ---------------- GAT aggregation: 4 nodes / 256-thread block --------------
// hb pair t = channels (t, t+64); lane l owns (l, l+64); hA = l>>5.
// Output raw1b: bf16, channel-ordered.
__global__ __launch_bounds__(256) void k_gat_aggr(
    const unsigned* __restrict__ hb, const float* __restrict__ aSg,
    const float* __restrict__ aDg, const int* __restrict__ offs,
    const int* __restrict__ csr, unsigned short* __restrict__ raw1b, int N)
{
    __shared__ __align__(16) float s_u[4][64][4];   // (u0,u2,u1,u3)
    __shared__ int s_s[4][64];

    const int wid = threadIdx.x >> 6;
    const int lane = threadIdx.x & 63;
    const int n = blockIdx.x * 4 + wid;
    if (n >= N) return;

    const int beg = offs[n];
    const int cnt = offs[n + 1] - beg + 1;          // + self loop
    const float4 ad = *(const float4*)(aDg + (size_t)n * 4);
    const int hA = lane >> 5;
    const float* pu = &s_u[wid][0][2 * hA];
    const int* ps = &s_s[wid][0];

    float t0 = 0.f, t1 = 0.f, t2 = 0.f, t3 = 0.f;
    float accLo = 0.f, accHi = 0.f;

    for (int base = 0; base < cnt; base += 64) {
        int idx = base + lane;
        bool valid = idx < cnt;
        int src = n;
        if (valid && idx > 0) src = csr[beg + idx - 1];
        float u0 = 0.f, u1 = 0.f, u2 = 0.f, u3 = 0.f;
        if (valid) {
            float4 as = *(const float4*)(aSg + (size_t)src * 4);
            float l0 = as.x + ad.x; l0 = (l0 > 0.f) ? l0 : NEG_SLOPE * l0;
            float l1 = as.y + ad.y; l1 = (l1 > 0.f) ? l1 : NEG_SLOPE * l1;
            float l2 = as.z + ad.z; l2 = (l2 > 0.f) ? l2 : NEG_SLOPE * l2;
            float l3 = as.w + ad.w; l3 = (l3 > 0.f) ? l3 : NEG_SLOPE * l3;
            u0 = __expf(l0); u1 = __expf(l1); u2 = __expf(l2); u3 = __expf(l3);
        }
        t0 += u0; t1 += u1; t2 += u2; t3 += u3;
        s_s[wid][lane] = src;
        *(float4*)&s_u[wid][lane][0] = make_float4(u0, u2, u1, u3);

        int cc = min(64, cnt - base);
        int j = 0;
        for (; j + 8 <= cc; j += 8) {
            int sj[8]; float2 uj[8]; unsigned vv[8];
#pragma unroll
            for (int k = 0; k < 8; k++) sj[k] = ps[j + k];
#pragma unroll
            for (int k = 0; k < 8; k++) uj[k] = *(const float2*)&pu[(j + k) * 4];
#pragma unroll
            for (int k = 0; k < 8; k++) vv[k] = hb[sj[k] * 64 + lane];
#pragma unroll
            for (int k = 0; k < 8; k++) {
                float lo = __uint_as_float(vv[k] << 16);
                float hi = __uint_as_float(vv[k] & 0xffff0000u);
                accLo += uj[k].x * lo;
                accHi += uj[k].y * hi;
            }
        }
        for (; j < cc; j++) {
            int sj = ps[j];
            float2 uv = *(const float2*)&pu[j * 4];
            unsigned v = hb[sj * 64 + lane];
            accLo += uv.x * __uint_as_float(v << 16);
            accHi += uv.y * __uint_as_float(v & 0xffff0000u);
        }
    }
#pragma unroll
    for (int msk = 1; msk < 64; msk <<= 1) {
        t0 += __shfl_xor(t0, msk);
        t1 += __shfl_xor(t1, msk);
        t2 += __shfl_xor(t2, msk);
        t3 += __shfl_xor(t3, msk);
    }
    float sLo = (hA ? t1 : t0) + 1e-16f;
    float sHi = (hA ? t3 : t2) + 1e-16f;
    raw1b[(size_t)n * 128 + lane]      = bf16_1(accLo / sLo);
    raw1b[(size_t)n * 128 + 64 + lane] = bf16_1(accHi / sHi);
}

// ---------------- GCN aggregation + fused BN2/ELU/gate/fc ------------------
__global__ __launch_bounds__(256) void k_gcn_aggr(
    const unsigned* __restrict__ h2b, const int* __restrict__ offs,
    const int* __restrict__ csr, const float* __restrict__ dinv,
    const float* __restrict__ bgcn,
    const float* __restrict__ bn2w, const float* __restrict__ bn2b,
    const float* __restrict__ wgate, const float* __restrict__ bgate,
    const float* __restrict__ wfc,
    float* __restrict__ gate, float* __restrict__ fcdot, int N)
{
    __shared__ int s_s[4][64];

    const int wid = threadIdx.x >> 6;
    const int lane = threadIdx.x & 63;
    const int n = blockIdx.x * 4 + wid;
    if (n >= N) return;

    const int beg = offs[n];
    const int cnt = offs[n + 1] - beg + 1;
    const float dn = dinv[n];
    const int* ps = &s_s[wid][0];

    float accLo = 0.f, accHi = 0.f;
    for (int base = 0; base < cnt; base += 64) {
        int idx = base + lane;
        int src = n;
        if (idx > 0 && idx < cnt) src = csr[beg + idx - 1];
        s_s[wid][lane] = src;

        int cc = min(64, cnt - base);
        int j = 0;
        for (; j + 8 <= cc; j += 8) {
            int sj[8]; unsigned vv[8];
#pragma unroll
            for (int k = 0; k < 8; k++) sj[k] = ps[j + k];
#pragma unroll
            for (int k = 0; k < 8; k++) vv[k] = h2b[sj[k] * 64 + lane];
#pragma unroll
            for (int k = 0; k < 8; k++) {
                accLo += __uint_as_float(vv[k] << 16);
                accHi += __uint_as_float(vv[k] & 0xffff0000u);
            }
        }
        for (; j < cc; j++) {
            unsigned v = h2b[ps[j] * 64 + lane];
            accLo += __uint_as_float(v << 16);
            accHi += __uint_as_float(v & 0xffff0000u);
        }
    }
    float v0 = dn * accLo + bgcn[lane];
    v0 = (v0 > 0.f) ? v0 : expm1f(v0);
    v0 = v0 * bn2w[lane] + bn2b[lane];
    float v1 = dn * accHi + bgcn[lane + 64];
    v1 = (v1 > 0.f) ? v1 : expm1f(v1);
    v1 = v1 * bn2w[lane + 64] + bn2b[lane + 64];

    float g = v0 * wgate[lane] + v1 * wgate[lane + 64];
    float f = v0 * wfc[lane]   + v1 * wfc[lane + 64];
#pragma unroll
    for (int msk = 1; msk < 64; msk <<= 1) {
        g += __shfl_xor(g, msk);
        f += __shfl_xor(f, msk);
    }
    if (lane == 0) { gate[n] = g + bgate[0]; fcdot[n] = f; }
}

// ---------------- pooling softmax over scalars: one block / graph ----------
__global__ __launch_bounds__(256) void k_pool(
    const float* __restrict__ gate, const float* __restrict__ fcdot,
    const int* __restrict__ batch, const float* __restrict__ bfc,
    float* __restrict__ out, int N)
{
    __shared__ float red[256];
    __shared__ int range[2];
    const int g = blockIdx.x;
    const int tid = threadIdx.x;
    if (tid < 2) range[tid] = lower_bound_i(batch, N, g + tid);
    __syncthreads();
    const int lo = range[0], hi = range[1];
    float se = 0.f, sf = 0.f;
    for (int i = lo + tid; i < hi; i += 256) {
        float e = __expf(gate[i]);
        se += e;
        sf += e * fcdot[i];
    }
    red[tid] = se; __syncthreads();
    for (int s = 128; s > 0; s >>= 1) {
        if (tid < s) red[tid] += red[tid + s];
        __syncthreads();
    }
    se = red[0]; __syncthreads();
    red[tid] = sf; __syncthreads();
    for (int s = 128; s > 0; s >>= 1) {
        if (tid < s) red[tid] += red[tid + s];
        __syncthreads();
    }
    sf = red[0];
    if (tid == 0) out[g] = sf / (se + 1e-16f) + bfc[0];
}

// ---------------------------------------------------------------------------
extern "C" void kernel_launch(void* const* d_in, const int* in_sizes, int n_in,
                              void* d_out, int out_size, void* d_ws, size_t ws_size,
                              hipStream_t stream) {
    const float* x     = (const float*)d_in[0];
    const int*   ei    = (const int*)d_in[1];
    const int*   batch = (const int*)d_in[2];
    const float* Wgat  = (const float*)d_in[3];
    const float* atts  = (const float*)d_in[4];
    const float* attd  = (const float*)d_in[5];
    const float* bgat  = (const float*)d_in[6];
    const float* bn1w  = (const float*)d_in[7];
    const float* bn1b  = (const float*)d_in[8];
    const float* Wgcn  = (const float*)d_in[9];
    const float* bgcn  = (const float*)d_in[10];
    const float* bn2w  = (const float*)d_in[11];
    const float* bn2b  = (const float*)d_in[12];
    const float* wgate = (const float*)d_in[13];
    const float* bgate = (const float*)d_in[14];
    const float* wfc   = (const float*)d_in[15];
    const float* bfc   = (const float*)d_in[16];
    float* out = (float*)d_out;

    const int N = in_sizes[0] / 128;
    const int E = in_sizes[1] / 2;
    const int NB = (N + BKT_SIZE - 1) / BKT_SIZE;
    const int NHB = (E + 2047) / 2048;             // hist blocks

    unsigned* hb  = (unsigned*)d_ws;               // bf16 h table   [N*64]
    unsigned* h2b = hb + (size_t)N * 64;           // bf16 h2s table [N*64]
    unsigned short* raw1b = (unsigned short*)(h2b + (size_t)N * 64); // [N*128]
    int2* pairs  = (int2*)raw1b;                   // aliased: pre-GAT only
    float* aS    = (float*)(raw1b + (size_t)N * 128); // [N*4]
    float* aD    = aS + (size_t)N * 4;             // [N*4]
    float* gate  = aD + (size_t)N * 4;             // [N]
    float* fcdot = gate + N;                       // [N]
    float* dinv  = fcdot + N;                      // [N]
    int* offs   = (int*)(dinv + N);                // [N+1]
    int* csr    = offs + (N + 1);                  // [E]
    int* bcount = csr + E;                         // [NB+1]
    int* bb     = bcount + (NB + 1);               // [NB+1]
    int* bcur   = bb + (NB + 1);                   // [NB+1]
    unsigned short* Wt1 = (unsigned short*)(bcur + (NB + 1)); // [144*128]
    unsigned short* Wt2 = Wt1 + 144 * 128;                    // [128*128]

    hipMemsetAsync(bcount, 0, (size_t)(NB + 1) * sizeof(int), stream);

    const int gemm_blocks = (N + 127) / 128;
    const int aggr_blocks = (N + 3) / 4;

    k_front<<<NHB + 2, 256, 0, stream>>>(Wgat, atts, attd, Wgcn, Wt1, Wt2,
                                         ei + E, bcount, E, NB);
    k_gemm_mfma<0><<<gemm_blocks, 256, 0, stream>>>(x, Wt1, hb, N,
                                                    nullptr, nullptr, nullptr,
                                                    nullptr, aS, aD);
    k_bscan<<<1, 512, 0, stream>>>(bcount, bb, bcur, NB);
    k_binA<<<(E + CHUNK_A - 1) / CHUNK_A, 256, 0, stream>>>(ei, bcur, pairs, E, NB);
    k_binB<<<NB, 256, 0, stream>>>(pairs, bb, csr, offs, dinv, N, NB, E);
    k_gat_aggr<<<aggr_blocks, 256, 0, stream>>>(hb, aS, aD, offs, csr, raw1b, N);
    k_gemm_mfma<1><<<gemm_blocks, 256, 0, stream>>>(raw1b, Wt2, h2b, N,
                                                    bgat, bn1w, bn1b, dinv,
                                                    nullptr, nullptr);
    k_gcn_aggr<<<aggr_blocks, 256, 0, stream>>>(h2b, offs, csr, dinv, bgcn,
                                                bn2w, bn2b, wgate, bgate, wfc,
                                                gate, fcdot, N);
    k_pool<<<64, 256, 0, stream>>>(gate, fcdot, batch, bfc, out, N);
}